// Round 13
// baseline (253.564 us; speedup 1.0000x reference)
//
#include <hip/hip_runtime.h>
#include <hip/hip_cooperative_groups.h>

// ---------------------------------------------------------------------------
// PointTransformerForSegmentation, round 18:
//   pre3 (cooperative, 256 blk x 512 thr, 1 grid.sync):
//     phase A: bf16 casts (w1b, w0p ONLY -- fgemm now reads f32 direct)
//              + kNN (4-thr/query scan + merge, serial tie order)
//              + pos embed -> posw/idxw
//     phase B: fgemm DIRECT-REG (per-wave 16x16 tile, global f32 -> cvt ->
//              MFMA, zero LDS) -> F
//     -- grid.sync() --
//     phase C: h0 streaming (R12 body): H0 = relu((F[idx]+posw.W0p^T)s0+b0)
//   gemm2  : R12 verbatim (67us proven): plane-interleaved byte-cut GEMM,
//            BM=128 x BN=256, BK=32, 3 live accumulators, B staged once,
//            triple-buffered 40KB units, counted vmcnt(5), 1 barrier/step.
// Rationale: ~100us/iter is dispatch-count-bound harness overhead (20
// dispatches); this cuts our launches 4 -> 2 and deletes two intermediate
// buffers (f2b, w0f) plus 786K conversion elements.
// ---------------------------------------------------------------------------

namespace cg = cooperative_groups;

typedef unsigned short u16;
typedef __bf16 bf16x8 __attribute__((ext_vector_type(8)));
typedef float f32x4 __attribute__((ext_vector_type(4)));
typedef u16 u16x4 __attribute__((ext_vector_type(4)));
typedef u16 u16x8 __attribute__((ext_vector_type(8)));

#define BQ 8
#define N1Q 2048
#define N2Q 128
#define C2Q 256
#define DPOS 32
#define H0Q 512
#define H1Q 1024
#define NQ (BQ * N1Q)   // 16384 queries

// workspace layout (bytes)
#define WS_W0P 262144u     // 512*32*2    = 32768
#define WS_W1 294912u      // 1024*512*2  = 1048576
#define WS_F 1867776u      // 1024*512*4  = 2097152
#define WS_H0 3964928u     // 3*16384*512*2 = 50331648
#define WS_POS 54296576u   // 3*16384*32*2 = 3145728
#define WS_IDX 57442304u   // 3*16384*4   = 196608 (end 57638912)

__device__ __forceinline__ u16 f2bf(float f) {
  unsigned int u = __builtin_bit_cast(unsigned int, f);
  return (u16)((u + 0x7FFFu + ((u >> 16) & 1u)) >> 16);
}

__device__ __forceinline__ void load16_lds(const void* g, void* l) {
  __builtin_amdgcn_global_load_lds(
      (const __attribute__((address_space(1))) unsigned int*)g,
      (__attribute__((address_space(3))) unsigned int*)l, 16, 0, 0);
}

// ---------------------------------------------------------------------------
// pre3: cooperative fused pre-pass. 256 blocks x 512 threads, co-resident.
__global__ __launch_bounds__(512, 2) void pre3(
    const float* __restrict__ xyz1, const float* __restrict__ xyz2,
    const float* __restrict__ lrf2, const float* __restrict__ w_pos,
    const float* __restrict__ pscale, const float* __restrict__ pbias,
    const float* __restrict__ w0, const float* __restrict__ w1,
    const float* __restrict__ feat2, const float* __restrict__ s0,
    const float* __restrict__ b0, u16* __restrict__ posw,
    int* __restrict__ idxw, u16* __restrict__ w0p, u16* __restrict__ w1b,
    float* __restrict__ F, u16* __restrict__ H0) {
  __shared__ float xyz2s[N2Q * 3];
  __shared__ float n2s[N2Q];
  __shared__ float lrfs[N2Q * 9];
  __shared__ float wps[DPOS * 4];
  __shared__ float pss[DPOS];
  __shared__ float pbs[DPOS];
  __shared__ float candd[64 * 13];  // stride 13: conflict-free merge reads
  __shared__ int candi[64 * 13];
  __shared__ int idxb[192];

  const int t = threadIdx.x;
  const int wv = t >> 6, lane = t & 63;
  const int quad = lane >> 4, cc = lane & 15;

  // ---- phase A1: conversions, vectorized f32x4 -> 4x bf16 ----
  // units: w1b 131072 vec4 + w0p 4096 vec4 = 135168; 131072 threads.
  {
    const int gtid = blockIdx.x * 512 + t;
    for (int j = gtid; j < 135168; j += 131072) {
      if (j < 131072) {
        f32x4 v = *(const f32x4*)(w1 + (size_t)j * 4);
        u16x4 o = {f2bf(v[0]), f2bf(v[1]), f2bf(v[2]), f2bf(v[3])};
        *(u16x4*)(w1b + (size_t)j * 4) = o;
      } else {
        int k = j - 131072;           // < 4096
        int h = k >> 3, c4 = k & 7;
        f32x4 v = *(const f32x4*)(w0 + h * 288 + 256 + c4 * 4);
        u16x4 o = {f2bf(v[0]), f2bf(v[1]), f2bf(v[2]), f2bf(v[3])};
        *(u16x4*)(w0p + h * 32 + c4 * 4) = o;
      }
    }
  }

  // ---- phase A2: kNN + pos embed, 64 queries per block ----
  const int qb = blockIdx.x * 64;
  const int b = qb >> 11;
  for (int i = t; i < N2Q * 3; i += 512) xyz2s[i] = xyz2[b * N2Q * 3 + i];
  for (int i = t; i < N2Q * 9; i += 512) lrfs[i] = lrf2[b * N2Q * 9 + i];
  if (t < DPOS * 4) wps[t] = w_pos[t];
  if (t < DPOS) { pss[t] = pscale[t]; pbs[t] = pbias[t]; }
  __syncthreads();
  if (t < N2Q) {
    float x = xyz2s[t * 3], y = xyz2s[t * 3 + 1], z = xyz2s[t * 3 + 2];
    n2s[t] = x * x + y * y + z * z;
  }
  __syncthreads();

  if (t < 256) {  // 1a: 4 threads/query scan 32 points each
    const int ql = t >> 2, qt = t & 3;
    const int q = qb + ql;
    const float px = xyz1[q * 3], py = xyz1[q * 3 + 1], pz = xyz1[q * 3 + 2];
    const float pn = px * px + py * py + pz * pz;
    float d0 = 1e30f, d1 = 1e30f, d2v = 1e30f;
    int i0 = 0, i1 = 0, i2 = 0;
    const int ibeg = qt * 32;
    for (int i = ibeg; i < ibeg + 32; i++) {
      float dt = px * xyz2s[i * 3] + py * xyz2s[i * 3 + 1] + pz * xyz2s[i * 3 + 2];
      float d = pn + n2s[i] - 2.f * dt;
      if (d < d0) {
        d2v = d1; i2 = i1; d1 = d0; i1 = i0; d0 = d; i0 = i;
      } else if (d < d1) {
        d2v = d1; i2 = i1; d1 = d; i1 = i;
      } else if (d < d2v) {
        d2v = d; i2 = i;
      }
    }
    int base = ql * 13 + qt * 3;
    candd[base] = d0;      candi[base] = i0;
    candd[base + 1] = d1;  candi[base + 1] = i1;
    candd[base + 2] = d2v; candi[base + 2] = i2;
  }
  __syncthreads();

  if (t < 64) {  // 1b: merge 12 candidates, qt-major == serial tie order
    float d0 = 1e30f, d1 = 1e30f, d2v = 1e30f;
    int i0 = 0, i1 = 0, i2 = 0;
    int base = t * 13;
#pragma unroll
    for (int c = 0; c < 12; c++) {
      float d = candd[base + c];
      int id = candi[base + c];
      if (d < d0) {
        d2v = d1; i2 = i1; d1 = d0; i1 = i0; d0 = d; i0 = id;
      } else if (d < d1) {
        d2v = d1; i2 = i1; d1 = d; i1 = id;
      } else if (d < d2v) {
        d2v = d; i2 = id;
      }
    }
    idxb[t] = i0;
    idxb[64 + t] = i1;
    idxb[128 + t] = i2;
  }
  __syncthreads();

  if (t < 192) {  // 1c: pos embed, one (query, neighbor) per thread
    const int j = t >> 6, ql = t & 63;
    const int q = qb + ql;
    const float px = xyz1[q * 3], py = xyz1[q * 3 + 1], pz = xyz1[q * 3 + 2];
    const int id = idxb[t];
    float rx = px - xyz2s[id * 3];
    float ry = py - xyz2s[id * 3 + 1];
    float rz = pz - xyz2s[id * 3 + 2];
    float rn = sqrtf(rx * rx + ry * ry + rz * rz);
    float inv = 1.f / fmaxf(rn, 1e-12f);
    float ux = rx * inv, uy = ry * inv, uz = rz * inv;
    const float* L = lrfs + id * 9;
    float a0 = L[0] * ux + L[1] * uy + L[2] * uz;
    float a1 = L[3] * ux + L[4] * uy + L[5] * uz;
    float a2 = L[6] * ux + L[7] * uy + L[8] * uz;
    const size_t row = (size_t)j * NQ + q;
    idxw[row] = id;
#pragma unroll
    for (int c = 0; c < 4; c++) {
      u16x8 chunk;
#pragma unroll
      for (int e = 0; e < 8; e++) {
        int o = c * 8 + e;
        float v = wps[o * 4] * rn + wps[o * 4 + 1] * a0 + wps[o * 4 + 2] * a1 +
                  wps[o * 4 + 3] * a2;
        v = v * pss[o] + pbs[o];
        v = (v >= 0.f) ? v : 0.2f * v;  // LeakyReLU(0.2)
        chunk[e] = f2bf(v);
      }
      *(u16x8*)(posw + row * 32 + c * 8) = chunk;
    }
  }

  // ---- phase B: fgemm direct-reg. 2048 waves = 2048 16x16 tiles of F ----
  {
    const int wid = blockIdx.x * 8 + wv;  // 0..2047
    const int m0 = (wid >> 5) * 16;       // 64 m-tiles
    const int n0 = (wid & 31) * 16;       // 32 n-tiles
    const float* fa0 = feat2 + (size_t)(m0 + cc) * 256 + quad * 8;
    const float* fb0 = w0 + (size_t)(n0 + cc) * 288 + quad * 8;
    f32x4 acc = {};
#pragma unroll
    for (int q8 = 0; q8 < 8; q8++) {
      u16x8 au, bu;
#pragma unroll
      for (int e = 0; e < 8; e++) {
        au[e] = f2bf(fa0[q8 * 32 + e]);
        bu[e] = f2bf(fb0[q8 * 32 + e]);
      }
      acc = __builtin_amdgcn_mfma_f32_16x16x32_bf16(
          __builtin_bit_cast(bf16x8, au), __builtin_bit_cast(bf16x8, bu), acc,
          0, 0, 0);
    }
#pragma unroll
    for (int r = 0; r < 4; r++)
      F[(size_t)(m0 + quad * 4 + r) * H0Q + n0 + cc] = acc[r];
  }

  cg::this_grid().sync();

  // ---- phase C: h0 streaming (R12 body), grid-stride over 3072 units ----
  {
    const int wid = blockIdx.x * 8 + wv;
    for (int u = wid; u < 3072; u += 2048) {
      const int r = u * 16 + cc;          // this lane's row
      const int q = r & (NQ - 1);
      const int bb = q >> 11;
      const int idv = idxw[r];
      const float* Fr = F + ((size_t)(bb * N2Q + idv)) * H0Q;
      u16* Hr = H0 + (size_t)r * H0Q;
      const bf16x8 afr = *(const bf16x8*)(posw + (size_t)r * 32 + quad * 8);
      const f32x4 zf = {};
#pragma unroll 4
      for (int nt = 0; nt < 32; nt++) {
        const bf16x8 bfr =
            *(const bf16x8*)(w0p + (nt * 16 + cc) * 32 + quad * 8);
        f32x4 acc =
            __builtin_amdgcn_mfma_f32_16x16x32_bf16(bfr, afr, zf, 0, 0, 0);
        const int hb = nt * 16 + quad * 4;
        const f32x4 sv = *(const f32x4*)(s0 + hb);
        const f32x4 bv = *(const f32x4*)(b0 + hb);
        const f32x4 fv = *(const f32x4*)(Fr + hb);
        u16x4 o4;
#pragma unroll
        for (int e = 0; e < 4; e++) {
          float h = (fv[e] + acc[e]) * sv[e] + bv[e];
          h = h > 0.f ? h : 0.f;
          o4[e] = f2bf(h);
        }
        *(u16x4*)(Hr + hb) = o4;
      }
    }
  }
}

// ---------------------------------------------------------------------------
// gemm2 (R12 verbatim, 67us champion): plane-interleaved byte-cut GEMM.
// BM=128 x BN=256, BK=32, 16 K-steps; per step stage {A-plane0,1,2 (24KB) +
// B (16KB)} with B staged ONCE (planes inner, 3 live accumulators).
// Triple-buffered 40KB units (120KB LDS), counted vmcnt(5), 1 barrier/step.
// Epilogue: out = sum_j relu(acc_j*s1+b1).
__global__ __launch_bounds__(512, 2) void gemm2(const u16* __restrict__ A,
                                                const u16* __restrict__ W,
                                                const float* __restrict__ s,
                                                const float* __restrict__ bz,
                                                float* __restrict__ out) {
  __shared__ alignas(16) char smem[3][40960];  // A 3x8KB + B 16KB per buffer
  const int id = blockIdx.x;            // 512 blocks
  const int xcd = id & 7, g = id >> 3;  // g 0..63
  const int m0 = (xcd * 16 + (g >> 2)) * 128;  // 16 m-tiles per XCD
  const int n0 = (g & 3) * 256;
  const int t = threadIdx.x;
  const int wv = t >> 6, lane = t & 63;
  const int wm = wv >> 2, wn = wv & 3;  // 2M x 4N wave grid, 64x64 per wave
  const int quad = lane >> 4, cc = lane & 15;
  const int lr = lane & 15, lk = quad * 8;

  // staging source bases (elements); +kt*32 per step; A: +plane*NQ*H0Q
  const size_t aOff = (size_t)(m0 + wv * 16 + lr) * 512 + lk;
  size_t bOff[2];
#pragma unroll
  for (int i = 0; i < 2; i++)
    bOff[i] = (size_t)(n0 + (wv * 2 + i) * 16 + lr) * 512 + lk;

  auto stage = [&](int kt, int buf) {
    const int k0 = kt << 5;
    char* dst = smem[buf] + (lane << 4);
#pragma unroll
    for (int j = 0; j < 3; j++)
      load16_lds(A + (size_t)j * NQ * H0Q + aOff + k0,
                 dst + j * 8192 + wv * 1024);
#pragma unroll
    for (int i = 0; i < 2; i++)
      load16_lds(W + bOff[i] + k0, dst + 24576 + (wv * 2 + i) * 1024);
  };

  f32x4 acc[3][4][4] = {};  // 192 VGPR: 3 planes x 64x64 wave tile

  stage(0, 0);
  stage(1, 1);

  int bi = 0, sb = 2;
  for (int kt = 0; kt < 16; kt++) {
    if (kt < 15)
      asm volatile("s_waitcnt vmcnt(5)" ::: "memory");  // tile kt landed
    else
      asm volatile("s_waitcnt vmcnt(0)" ::: "memory");
    __builtin_amdgcn_s_barrier();  // all waves past step kt-1 (reads done)
    if (kt + 2 < 16) {
      stage(kt + 2, sb);           // overwrite buf of tile kt-1: safe
      sb = (sb == 2) ? 0 : sb + 1;
    }
    const char* base = smem[bi] + (lane << 4);
    bf16x8 bf[4];
#pragma unroll
    for (int nt = 0; nt < 4; nt++)
      bf[nt] = *(const bf16x8*)(base + 24576 + (wn * 4 + nt) * 1024);
#pragma unroll
    for (int j = 0; j < 3; j++) {
      bf16x8 af[4];
#pragma unroll
      for (int mt = 0; mt < 4; mt++)
        af[mt] = *(const bf16x8*)(base + j * 8192 + (wm * 4 + mt) * 1024);
      __builtin_amdgcn_s_setprio(1);
#pragma unroll
      for (int mt = 0; mt < 4; mt++)
#pragma unroll
        for (int nt = 0; nt < 4; nt++)
          acc[j][mt][nt] = __builtin_amdgcn_mfma_f32_16x16x32_bf16(
              af[mt], bf[nt], acc[j][mt][nt], 0, 0, 0);
      __builtin_amdgcn_s_setprio(0);
    }
    bi = (bi == 2) ? 0 : bi + 1;
  }

  // epilogue: out = sum_j relu(acc_j * s1 + b1)
#pragma unroll
  for (int nt = 0; nt < 4; nt++) {
    int gn = n0 + wn * 64 + nt * 16 + cc;
    float sv = s[gn], bv = bz[gn];
#pragma unroll
    for (int mt = 0; mt < 4; mt++) {
      int gm = m0 + wm * 64 + mt * 16 + quad * 4;
#pragma unroll
      for (int r = 0; r < 4; r++) {
        float h0v = acc[0][mt][nt][r] * sv + bv;
        float h1v = acc[1][mt][nt][r] * sv + bv;
        float h2v = acc[2][mt][nt][r] * sv + bv;
        float v = (h0v > 0.f ? h0v : 0.f) + (h1v > 0.f ? h1v : 0.f) +
                  (h2v > 0.f ? h2v : 0.f);
        int q = gm + r;
        out[((size_t)(q >> 11) * H1Q + gn) * N1Q + (q & 2047)] = v;
      }
    }
  }
}

// ---------------------------------------------------------------------------
extern "C" void kernel_launch(void* const* d_in, const int* in_sizes, int n_in,
                              void* d_out, int out_size, void* d_ws,
                              size_t ws_size, hipStream_t stream) {
  const float* xyz1 = (const float*)d_in[0];
  const float* xyz2 = (const float*)d_in[1];
  const float* feat2 = (const float*)d_in[2];
  const float* lrf2 = (const float*)d_in[3];
  const float* w_pos = (const float*)d_in[4];
  const float* pscale = (const float*)d_in[5];
  const float* pbias = (const float*)d_in[6];
  const float* w0 = (const float*)d_in[7];
  const float* s0 = (const float*)d_in[8];
  const float* b0 = (const float*)d_in[9];
  const float* w1 = (const float*)d_in[10];
  const float* s1 = (const float*)d_in[11];
  const float* b1 = (const float*)d_in[12];
  float* out = (float*)d_out;

  char* ws = (char*)d_ws;
  u16* w0p = (u16*)(ws + WS_W0P);
  u16* w1b = (u16*)(ws + WS_W1);
  float* F = (float*)(ws + WS_F);
  u16* H0 = (u16*)(ws + WS_H0);
  u16* posw = (u16*)(ws + WS_POS);
  int* idxw = (int*)(ws + WS_IDX);

  void* args[] = {&xyz1, &xyz2,  &lrf2, &w_pos, &pscale, &pbias,
                  &w0,   &w1,    &feat2, &s0,   &b0,     &posw,
                  &idxw, &w0p,   &w1b,  &F,     &H0};
  hipLaunchCooperativeKernel((void*)pre3, dim3(256), dim3(512), args, 0,
                             stream);
  gemm2<<<512, 512, 0, stream>>>(H0, w1b, s1, b1, out);
}

// Round 14
// 196.603 us; speedup vs baseline: 1.2897x; 1.2897x over previous
//
#include <hip/hip_runtime.h>

// ---------------------------------------------------------------------------
// PointTransformerForSegmentation, round 19 (recover R12 + safe fusions):
//   prep  : ONE regular launch, blockIdx-partitioned:
//           blocks 0..127   kNN (4thr/query + merge, serial tie order) +
//                           pos embed -> posw/idxw
//           blocks 128..391 vectorized f32x4->bf16x4 casts (w1b, w0p only)
//           blocks 392..647 fgemm DIRECT-REG (per-wave 16x16 tile of
//                           F = feat2 . W0feat^T, f32 reads, zero LDS)
//   h0    : R12 verbatim: streaming H0 = relu((F[idx]+posw.W0p^T)s0+b0),
//           zero LDS, 768 blocks x 256 thr.
//   gemm2 : R12 verbatim (67us proven): plane-interleaved byte-cut GEMM,
//           BM=128 x BN=256, BK=32, 3 live accumulators, B staged once,
//           triple-buffered 40KB units, counted vmcnt(5), 1 barrier/step.
// R13 lesson: cooperative launch breaks graph-captured replay (+50us) and
// 1-block/CU co-residency starves the streaming phase -> regular launches.
// ---------------------------------------------------------------------------

typedef unsigned short u16;
typedef __bf16 bf16x8 __attribute__((ext_vector_type(8)));
typedef float f32x4 __attribute__((ext_vector_type(4)));
typedef u16 u16x4 __attribute__((ext_vector_type(4)));
typedef u16 u16x8 __attribute__((ext_vector_type(8)));

#define BQ 8
#define N1Q 2048
#define N2Q 128
#define C2Q 256
#define DPOS 32
#define H0Q 512
#define H1Q 1024
#define NQ (BQ * N1Q)   // 16384 queries

// workspace layout (bytes)
#define WS_W0P 262144u     // 512*32*2    = 32768
#define WS_W1 294912u      // 1024*512*2  = 1048576
#define WS_F 1867776u      // 1024*512*4  = 2097152
#define WS_H0 3964928u     // 3*16384*512*2 = 50331648
#define WS_POS 54296576u   // 3*16384*32*2 = 3145728
#define WS_IDX 57442304u   // 3*16384*4   = 196608 (end 57638912)

__device__ __forceinline__ u16 f2bf(float f) {
  unsigned int u = __builtin_bit_cast(unsigned int, f);
  return (u16)((u + 0x7FFFu + ((u >> 16) & 1u)) >> 16);
}

__device__ __forceinline__ void load16_lds(const void* g, void* l) {
  __builtin_amdgcn_global_load_lds(
      (const __attribute__((address_space(1))) unsigned int*)g,
      (__attribute__((address_space(3))) unsigned int*)l, 16, 0, 0);
}

// ---------------------------------------------------------------------------
// prep: blocks 0..127 kNN+pos; 128..391 conversions (vec4); 392..647 fgemm.
__global__ __launch_bounds__(512, 2) void prep(
    const float* __restrict__ xyz1, const float* __restrict__ xyz2,
    const float* __restrict__ lrf2, const float* __restrict__ w_pos,
    const float* __restrict__ pscale, const float* __restrict__ pbias,
    const float* __restrict__ w0, const float* __restrict__ w1,
    const float* __restrict__ feat2,
    u16* __restrict__ posw, int* __restrict__ idxw,
    u16* __restrict__ w0p, u16* __restrict__ w1b, float* __restrict__ F) {
  const int t = threadIdx.x;

  if (blockIdx.x >= 392) {
    // ---- fgemm direct-reg: 2048 waves = 2048 16x16 tiles of F ----
    const int wv = t >> 6, lane = t & 63;
    const int quad = lane >> 4, cc = lane & 15;
    const int wid = (blockIdx.x - 392) * 8 + wv;  // 0..2047
    const int m0 = (wid >> 5) * 16;               // 64 m-tiles
    const int n0 = (wid & 31) * 16;               // 32 n-tiles
    const float* fa0 = feat2 + (size_t)(m0 + cc) * 256 + quad * 8;
    const float* fb0 = w0 + (size_t)(n0 + cc) * 288 + quad * 8;
    f32x4 acc = {};
#pragma unroll
    for (int q8 = 0; q8 < 8; q8++) {
      u16x8 au, bu;
#pragma unroll
      for (int e = 0; e < 8; e++) {
        au[e] = f2bf(fa0[q8 * 32 + e]);
        bu[e] = f2bf(fb0[q8 * 32 + e]);
      }
      acc = __builtin_amdgcn_mfma_f32_16x16x32_bf16(
          __builtin_bit_cast(bf16x8, au), __builtin_bit_cast(bf16x8, bu), acc,
          0, 0, 0);
    }
#pragma unroll
    for (int r = 0; r < 4; r++)
      F[(size_t)(m0 + quad * 4 + r) * H0Q + n0 + cc] = acc[r];
    return;
  }

  if (blockIdx.x >= 128) {
    // ---- conversions: 135168 vec4 units (w1b 131072 + w0p 4096) ----
    int j = (blockIdx.x - 128) * 512 + t;  // < 135168 exactly
    if (j < 131072) {
      f32x4 v = *(const f32x4*)(w1 + (size_t)j * 4);
      u16x4 o = {f2bf(v[0]), f2bf(v[1]), f2bf(v[2]), f2bf(v[3])};
      *(u16x4*)(w1b + (size_t)j * 4) = o;
    } else {
      int k = j - 131072;           // < 4096
      int h = k >> 3, c4 = k & 7;
      f32x4 v = *(const f32x4*)(w0 + h * 288 + 256 + c4 * 4);
      u16x4 o = {f2bf(v[0]), f2bf(v[1]), f2bf(v[2]), f2bf(v[3])};
      *(u16x4*)(w0p + h * 32 + c4 * 4) = o;
    }
    return;
  }

  // ---- kNN + pos embed: 128 queries per block ----
  __shared__ float xyz2s[N2Q * 3];
  __shared__ float n2s[N2Q];
  __shared__ float lrfs[N2Q * 9];
  __shared__ float wps[DPOS * 4];
  __shared__ float pss[DPOS];
  __shared__ float pbs[DPOS];
  __shared__ float candd[128 * 13];  // stride 13: conflict-free merge reads
  __shared__ int candi[128 * 13];
  __shared__ int idxb[384];

  const int qb = blockIdx.x * 128;
  const int b = qb >> 11;

  for (int i = t; i < N2Q * 3; i += 512) xyz2s[i] = xyz2[b * N2Q * 3 + i];
  for (int i = t; i < N2Q * 9; i += 512) lrfs[i] = lrf2[b * N2Q * 9 + i];
  if (t < DPOS * 4) wps[t] = w_pos[t];
  if (t < DPOS) { pss[t] = pscale[t]; pbs[t] = pbias[t]; }
  __syncthreads();
  if (t < N2Q) {
    float x = xyz2s[t * 3], y = xyz2s[t * 3 + 1], z = xyz2s[t * 3 + 2];
    n2s[t] = x * x + y * y + z * z;
  }
  __syncthreads();

  // ---- 1a: partial kNN, 4 threads per query ----
  {
    const int ql = t >> 2, qt = t & 3;
    const int q = qb + ql;
    const float px = xyz1[q * 3], py = xyz1[q * 3 + 1], pz = xyz1[q * 3 + 2];
    const float pn = px * px + py * py + pz * pz;
    float d0 = 1e30f, d1 = 1e30f, d2v = 1e30f;
    int i0 = 0, i1 = 0, i2 = 0;
    const int ibeg = qt * 32;
    for (int i = ibeg; i < ibeg + 32; i++) {
      float dt = px * xyz2s[i * 3] + py * xyz2s[i * 3 + 1] + pz * xyz2s[i * 3 + 2];
      float d = pn + n2s[i] - 2.f * dt;
      if (d < d0) {
        d2v = d1; i2 = i1; d1 = d0; i1 = i0; d0 = d; i0 = i;
      } else if (d < d1) {
        d2v = d1; i2 = i1; d1 = d; i1 = i;
      } else if (d < d2v) {
        d2v = d; i2 = i;
      }
    }
    int base = ql * 13 + qt * 3;
    candd[base] = d0;      candi[base] = i0;
    candd[base + 1] = d1;  candi[base + 1] = i1;
    candd[base + 2] = d2v; candi[base + 2] = i2;
  }
  __syncthreads();

  // ---- 1b: merge 12 candidates per query (t<128), serial tie order ----
  if (t < 128) {
    float d0 = 1e30f, d1 = 1e30f, d2v = 1e30f;
    int i0 = 0, i1 = 0, i2 = 0;
    int base = t * 13;
#pragma unroll
    for (int c = 0; c < 12; c++) {
      float d = candd[base + c];
      int id = candi[base + c];
      if (d < d0) {
        d2v = d1; i2 = i1; d1 = d0; i1 = i0; d0 = d; i0 = id;
      } else if (d < d1) {
        d2v = d1; i2 = i1; d1 = d; i1 = id;
      } else if (d < d2v) {
        d2v = d; i2 = id;
      }
    }
    idxb[t] = i0;
    idxb[128 + t] = i1;
    idxb[256 + t] = i2;
  }
  __syncthreads();

  // ---- 1c: pos embed, one (query, neighbor) per thread (t<384) ----
  if (t < 384) {
    const int j = t >> 7, ql = t & 127;
    const int q = qb + ql;
    const float px = xyz1[q * 3], py = xyz1[q * 3 + 1], pz = xyz1[q * 3 + 2];
    const int id = idxb[j * 128 + ql];
    float rx = px - xyz2s[id * 3];
    float ry = py - xyz2s[id * 3 + 1];
    float rz = pz - xyz2s[id * 3 + 2];
    float rn = sqrtf(rx * rx + ry * ry + rz * rz);
    float inv = 1.f / fmaxf(rn, 1e-12f);
    float ux = rx * inv, uy = ry * inv, uz = rz * inv;
    const float* L = lrfs + id * 9;
    float a0 = L[0] * ux + L[1] * uy + L[2] * uz;
    float a1 = L[3] * ux + L[4] * uy + L[5] * uz;
    float a2 = L[6] * ux + L[7] * uy + L[8] * uz;
    const size_t row = (size_t)j * NQ + q;
    idxw[row] = id;
#pragma unroll
    for (int c = 0; c < 4; c++) {
      u16x8 chunk;
#pragma unroll
      for (int e = 0; e < 8; e++) {
        int o = c * 8 + e;
        float v = wps[o * 4] * rn + wps[o * 4 + 1] * a0 + wps[o * 4 + 2] * a1 +
                  wps[o * 4 + 3] * a2;
        v = v * pss[o] + pbs[o];
        v = (v >= 0.f) ? v : 0.2f * v;  // LeakyReLU(0.2)
        chunk[e] = f2bf(v);
      }
      *(u16x8*)(posw + row * 32 + c * 8) = chunk;
    }
  }
}

// ---------------------------------------------------------------------------
// h0: streaming H0 build, zero LDS, 768 blocks x 256 threads (4 waves).
__global__ __launch_bounds__(256, 4) void h0_kernel(
    const u16* __restrict__ posw, const int* __restrict__ idxw,
    const u16* __restrict__ w0p, const float* __restrict__ F,
    const float* __restrict__ s0, const float* __restrict__ b0,
    u16* __restrict__ H0) {
  const int t = threadIdx.x;
  const int wv = t >> 6, lane = t & 63;
  const int quad = lane >> 4, cc = lane & 15;
  const int r0 = (blockIdx.x * 4 + wv) * 16;  // 768*4*16 = 49152 rows

  const int r = r0 + cc;               // this lane's row
  const int q = r & (NQ - 1);
  const int bb = q >> 11;
  const int idv = idxw[r];
  const float* Fr = F + ((size_t)(bb * N2Q + idv)) * H0Q;
  u16* Hr = H0 + (size_t)r * H0Q;

  const bf16x8 afr = *(const bf16x8*)(posw + (size_t)r * 32 + quad * 8);
  const f32x4 zf = {};

#pragma unroll 4
  for (int nt = 0; nt < 32; nt++) {
    const bf16x8 bfr = *(const bf16x8*)(w0p + (nt * 16 + cc) * 32 + quad * 8);
    f32x4 acc = __builtin_amdgcn_mfma_f32_16x16x32_bf16(bfr, afr, zf, 0, 0, 0);
    const int hb = nt * 16 + quad * 4;
    const f32x4 sv = *(const f32x4*)(s0 + hb);
    const f32x4 bv = *(const f32x4*)(b0 + hb);
    const f32x4 fv = *(const f32x4*)(Fr + hb);
    u16x4 o4;
#pragma unroll
    for (int e = 0; e < 4; e++) {
      float h = (fv[e] + acc[e]) * sv[e] + bv[e];
      h = h > 0.f ? h : 0.f;
      o4[e] = f2bf(h);
    }
    *(u16x4*)(Hr + hb) = o4;
  }
}

// ---------------------------------------------------------------------------
// gemm2 (R12 verbatim, 67us champion): plane-interleaved byte-cut GEMM.
// BM=128 x BN=256, BK=32, 16 K-steps; per step stage {A-plane0,1,2 (24KB) +
// B (16KB)} with B staged ONCE (planes inner, 3 live accumulators).
// Triple-buffered 40KB units (120KB LDS), counted vmcnt(5), 1 barrier/step.
// Epilogue: out = sum_j relu(acc_j*s1+b1).
__global__ __launch_bounds__(512, 2) void gemm2(const u16* __restrict__ A,
                                                const u16* __restrict__ W,
                                                const float* __restrict__ s,
                                                const float* __restrict__ bz,
                                                float* __restrict__ out) {
  __shared__ alignas(16) char smem[3][40960];  // A 3x8KB + B 16KB per buffer
  const int id = blockIdx.x;            // 512 blocks
  const int xcd = id & 7, g = id >> 3;  // g 0..63
  const int m0 = (xcd * 16 + (g >> 2)) * 128;  // 16 m-tiles per XCD
  const int n0 = (g & 3) * 256;
  const int t = threadIdx.x;
  const int wv = t >> 6, lane = t & 63;
  const int wm = wv >> 2, wn = wv & 3;  // 2M x 4N wave grid, 64x64 per wave
  const int quad = lane >> 4, cc = lane & 15;
  const int lr = lane & 15, lk = quad * 8;

  // staging source bases (elements); +kt*32 per step; A: +plane*NQ*H0Q
  const size_t aOff = (size_t)(m0 + wv * 16 + lr) * 512 + lk;
  size_t bOff[2];
#pragma unroll
  for (int i = 0; i < 2; i++)
    bOff[i] = (size_t)(n0 + (wv * 2 + i) * 16 + lr) * 512 + lk;

  auto stage = [&](int kt, int buf) {
    const int k0 = kt << 5;
    char* dst = smem[buf] + (lane << 4);
#pragma unroll
    for (int j = 0; j < 3; j++)
      load16_lds(A + (size_t)j * NQ * H0Q + aOff + k0,
                 dst + j * 8192 + wv * 1024);
#pragma unroll
    for (int i = 0; i < 2; i++)
      load16_lds(W + bOff[i] + k0, dst + 24576 + (wv * 2 + i) * 1024);
  };

  f32x4 acc[3][4][4] = {};  // 192 VGPR: 3 planes x 64x64 wave tile

  stage(0, 0);
  stage(1, 1);

  int bi = 0, sb = 2;
  for (int kt = 0; kt < 16; kt++) {
    if (kt < 15)
      asm volatile("s_waitcnt vmcnt(5)" ::: "memory");  // tile kt landed
    else
      asm volatile("s_waitcnt vmcnt(0)" ::: "memory");
    __builtin_amdgcn_s_barrier();  // all waves past step kt-1 (reads done)
    if (kt + 2 < 16) {
      stage(kt + 2, sb);           // overwrite buf of tile kt-1: safe
      sb = (sb == 2) ? 0 : sb + 1;
    }
    const char* base = smem[bi] + (lane << 4);
    bf16x8 bf[4];
#pragma unroll
    for (int nt = 0; nt < 4; nt++)
      bf[nt] = *(const bf16x8*)(base + 24576 + (wn * 4 + nt) * 1024);
#pragma unroll
    for (int j = 0; j < 3; j++) {
      bf16x8 af[4];
#pragma unroll
      for (int mt = 0; mt < 4; mt++)
        af[mt] = *(const bf16x8*)(base + j * 8192 + (wm * 4 + mt) * 1024);
      __builtin_amdgcn_s_setprio(1);
#pragma unroll
      for (int mt = 0; mt < 4; mt++)
#pragma unroll
        for (int nt = 0; nt < 4; nt++)
          acc[j][mt][nt] = __builtin_amdgcn_mfma_f32_16x16x32_bf16(
              af[mt], bf[nt], acc[j][mt][nt], 0, 0, 0);
      __builtin_amdgcn_s_setprio(0);
    }
    bi = (bi == 2) ? 0 : bi + 1;
  }

  // epilogue: out = sum_j relu(acc_j * s1 + b1)
#pragma unroll
  for (int nt = 0; nt < 4; nt++) {
    int gn = n0 + wn * 64 + nt * 16 + cc;
    float sv = s[gn], bv = bz[gn];
#pragma unroll
    for (int mt = 0; mt < 4; mt++) {
      int gm = m0 + wm * 64 + mt * 16 + quad * 4;
#pragma unroll
      for (int r = 0; r < 4; r++) {
        float h0v = acc[0][mt][nt][r] * sv + bv;
        float h1v = acc[1][mt][nt][r] * sv + bv;
        float h2v = acc[2][mt][nt][r] * sv + bv;
        float v = (h0v > 0.f ? h0v : 0.f) + (h1v > 0.f ? h1v : 0.f) +
                  (h2v > 0.f ? h2v : 0.f);
        int q = gm + r;
        out[((size_t)(q >> 11) * H1Q + gn) * N1Q + (q & 2047)] = v;
      }
    }
  }
}

// ---------------------------------------------------------------------------
extern "C" void kernel_launch(void* const* d_in, const int* in_sizes, int n_in,
                              void* d_out, int out_size, void* d_ws,
                              size_t ws_size, hipStream_t stream) {
  const float* xyz1 = (const float*)d_in[0];
  const float* xyz2 = (const float*)d_in[1];
  const float* feat2 = (const float*)d_in[2];
  const float* lrf2 = (const float*)d_in[3];
  const float* w_pos = (const float*)d_in[4];
  const float* pscale = (const float*)d_in[5];
  const float* pbias = (const float*)d_in[6];
  const float* w0 = (const float*)d_in[7];
  const float* s0 = (const float*)d_in[8];
  const float* b0 = (const float*)d_in[9];
  const float* w1 = (const float*)d_in[10];
  const float* s1 = (const float*)d_in[11];
  const float* b1 = (const float*)d_in[12];
  float* out = (float*)d_out;

  char* ws = (char*)d_ws;
  u16* w0p = (u16*)(ws + WS_W0P);
  u16* w1b = (u16*)(ws + WS_W1);
  float* F = (float*)(ws + WS_F);
  u16* H0 = (u16*)(ws + WS_H0);
  u16* posw = (u16*)(ws + WS_POS);
  int* idxw = (int*)(ws + WS_IDX);

  prep<<<648, 512, 0, stream>>>(xyz1, xyz2, lrf2, w_pos, pscale, pbias, w0,
                                w1, feat2, posw, idxw, w0p, w1b, F);
  h0_kernel<<<768, 256, 0, stream>>>(posw, idxw, w0p, F, s0, b0, H0);
  gemm2<<<512, 512, 0, stream>>>(H0, w1b, s1, b1, out);
}